// Round 9
// baseline (226.592 us; speedup 1.0000x reference)
//
#include <hip/hip_runtime.h>
#include <math.h>

#define HIDDEN   2048
#define NEXPERT  64
#define TOPK     8
#define NTOK     16384
#define TOKB     64          // tokens per block (four 16-row M tiles)
#define RSQRT_H  0.02209708691207961
#define WSCALE   64.0f       // keeps f16 Wl split in normal range; undone in epilogue

typedef __attribute__((ext_vector_type(8))) _Float16       v8h;
typedef __attribute__((ext_vector_type(8))) unsigned short v8u;
typedef __attribute__((ext_vector_type(4))) float          v4f;

static __device__ __forceinline__ unsigned short f16b(float x) {
    return __builtin_bit_cast(unsigned short, (_Float16)x);   // v_cvt_f16_f32 (RNE)
}
static __device__ __forceinline__ float f16f(unsigned short u) {
    return (float)__builtin_bit_cast(_Float16, u);
}

// Weight prep into B-fragment order: wf[ks(64)][nt(4)][hl(2)][lane(64)][j(8)] f16.
// B[k][n]: n = nt*16 + (lane&15), k = ks*32 + (lane>>4)*8 + j.  v = w*scale*64.
// Also zeroes out_c (replaces a separate hipMemsetAsync dispatch).
__global__ __launch_bounds__(256) void prep_wf(
    const float* __restrict__ w, const float* __restrict__ scale,
    unsigned short* __restrict__ wf, float* __restrict__ out_c)
{
    int i    = blockIdx.x * 256 + threadIdx.x;   // 131072
    if (i < NEXPERT) out_c[i] = 0.f;
    int j    = i & 7;
    int lane = (i >> 3) & 63;
    int nt   = (i >> 9) & 3;
    int ks   = i >> 11;
    int e    = nt * 16 + (lane & 15);
    int k    = ks * 32 + (lane >> 4) * 8 + j;
    float v  = w[e * HIDDEN + k] * scale[k] * WSCALE;
    unsigned short vh = f16b(v);
    unsigned short vl = f16b(v - f16f(vh));      // Dekker split: v - hi exact in f32
    size_t base = (((size_t)(ks * 4 + nt) * 2) * 64 + lane) * 8 + j;
    wf[base]       = vh;                          // hl=0
    wf[base + 512] = vl;                          // hl=1 (stride 64*8)
}

// Convert 8 f32 -> split-f16 hi/lo fragments; accumulate sum of squares.
static __device__ __forceinline__ void cvt8(
    v4f a, v4f b, v8h& ah, v8h& al, float& ss)
{
    float vv[8] = {a[0], a[1], a[2], a[3], b[0], b[1], b[2], b[3]};
    v8u uh, ul;
#pragma unroll
    for (int j = 0; j < 8; ++j) {
        float v = vv[j];
        unsigned short hh = f16b(v);
        uh[j] = hh;
        ul[j] = f16b(v - f16f(hh));   // exact residual in f32, then RNE
        ss    = fmaf(v, v, ss);
    }
    ah = __builtin_bit_cast(v8h, uh);
    al = __builtin_bit_cast(v8h, ul);
}

// 64 tokens/block, 1024 thr (16 waves), grid 256 = exactly 1 block/CU.
// Wave w = (tile t = w>>2, k-quarter kq = w&3): ONE 16-token M tile x 512 k.
// This reaches TOKB=64's wf-traffic halving (512 KB unique per block x 256
// blocks = 128 MB, vs R3/R8's 256 MB) at a per-wave register footprint that
// cannot spill: acc 16 + B 32 + X 16 + temps ~= 100 < 128 (R4-R6's TOKB=64
// attempts spilled because one wave held 4 tiles -> acc 64). The 4 waves
// sharing a kq read identical B bytes concurrently -> L1/L2 dedup.
// 16 waves/CU (R3's proven occupancy). X loads stay NON-TEMPORAL (stream-
// once; don't evict wf from L2/L3). 4 kq partials per token combined in LDS
// with the same pairwise reduction tree as R7/R8.
// logits_raw = Xh*Wh + Xh*Wl + Xl*Wh  (split-f16, per-acc order unchanged).
__global__ __launch_bounds__(1024, 1) void router_main(
    const float* __restrict__ h, const unsigned short* __restrict__ wf,
    const float* __restrict__ pes,
    float* __restrict__ out_w, float* __restrict__ out_i, float* __restrict__ out_c)
{
    __shared__ __align__(16) float lg[4 * 64 * 66];   // [kq][token][expert+pad] 67584B
    __shared__ float lss[4 * 64];                     // [kq][token] partial sumsq
    __shared__ int   hist[NEXPERT];

    const int tid  = (int)threadIdx.x;
    const int w    = __builtin_amdgcn_readfirstlane(tid >> 6);   // wave 0..15
    const int lane = tid & 63;
    const int m    = lane & 15;                                   // A row idx
    const int quad = lane >> 4;
    const int t    = w >> 2;                                      // M tile 0..3
    const int kq   = w & 3;                                       // k-quarter 0..3
    const int t0   = (int)blockIdx.x * TOKB;

    if (tid < NEXPERT) hist[tid] = 0;

    // A source: row (t0 + t*16 + m), k = kq*512 + s*32 + quad*8 + j
    const float* xp = h + (size_t)(t0 + t * 16 + m) * HIDDEN + kq * 512 + quad * 8;
    // B source: ks = kq*16 + s; frag base = ks*4096 + nt*1024 (+512 for lo)
    const unsigned short* wq = wf + (size_t)(kq * 16) * 4096 + (size_t)lane * 8;

    v4f acc[4];
#pragma unroll
    for (int nt = 0; nt < 4; ++nt) acc[nt] = (v4f)0.f;
    float ss = 0.f;

    v4f xa = __builtin_nontemporal_load((const v4f*)xp);
    v4f xb = __builtin_nontemporal_load((const v4f*)(xp + 4));

#pragma unroll
    for (int s = 0; s < 16; ++s) {
        // ---- issue ALL memory for this step first (8 B-frags + 2 nt X), fence
        const unsigned short* bq = wq + (size_t)s * 4096;
        v8h bh[4], bl[4];
#pragma unroll
        for (int nt = 0; nt < 4; ++nt) {
            bh[nt] = *(const v8h*)(bq + nt * 1024);
            bl[nt] = *(const v8h*)(bq + nt * 1024 + 512);
        }
        v4f na, nb;
        if (s < 15) {
            na = __builtin_nontemporal_load((const v4f*)(xp + (s + 1) * 32));
            nb = __builtin_nontemporal_load((const v4f*)(xp + (s + 1) * 32 + 4));
        }
        __builtin_amdgcn_sched_barrier(0);   // loads above, consumers below

        // ---- convert current X (overlaps B-load latency), 12 MFMAs
        v8h ah, al;
        cvt8(xa, xb, ah, al, ss);
#pragma unroll
        for (int nt = 0; nt < 4; ++nt) {
            acc[nt] = __builtin_amdgcn_mfma_f32_16x16x32_f16(ah, bh[nt], acc[nt], 0, 0, 0);
            acc[nt] = __builtin_amdgcn_mfma_f32_16x16x32_f16(ah, bl[nt], acc[nt], 0, 0, 0);
            acc[nt] = __builtin_amdgcn_mfma_f32_16x16x32_f16(al, bh[nt], acc[nt], 0, 0, 0);
        }

        if (s < 15) { xa = na; xb = nb; }
    }

    // ---- sum of squares: lane holds quad's 128-float share of row (t*16+m)
    {
        float s = ss;
        s += __shfl_xor(s, 16, 64);
        s += __shfl_xor(s, 32, 64);
        if (lane < 16) lss[kq * 64 + t * 16 + lane] = s;
    }

    // ---- raw logit partials: D row=(quad*4+reg)=token-in-tile, col=nt*16+m
#pragma unroll
    for (int nt = 0; nt < 4; ++nt)
#pragma unroll
        for (int r = 0; r < 4; ++r)
            lg[(kq * 64 + t * 16 + quad * 4 + r) * 66 + nt * 16 + m] = acc[nt][r];
    __syncthreads();

    // ---- top-8 epilogue (R0-verified): wave w handles tokens w*4..w*4+3
    for (int i = 0; i < 4; ++i) {
        const int tok = w * 4 + i;
        float lsum = (lg[(0 * 64 + tok) * 66 + lane] + lg[(1 * 64 + tok) * 66 + lane])
                   + (lg[(2 * 64 + tok) * 66 + lane] + lg[(3 * 64 + tok) * 66 + lane]);
        float sst4 = (lss[tok] + lss[64 + tok]) + (lss[128 + tok] + lss[192 + tok]);
        double sst = (double)sst4;
        double rr  = 1.0 / sqrt(sst * (1.0 / (double)HIDDEN) + 1e-6);
        float logit = (float)((double)lsum * rr * (RSQRT_H / (double)WSCALE));

        float work = logit;
        float myval = 0.f; int myidx = 0; float m0 = 0.f;
#pragma unroll
        for (int j = 0; j < TOPK; ++j) {
            float mx = work;
#pragma unroll
            for (int off = 32; off; off >>= 1) mx = fmaxf(mx, __shfl_xor(mx, off, 64));
            unsigned long long msk = __ballot(work == mx);
            int src = __ffsll((long long)msk) - 1;   // ties -> lowest index (jax)
            if (j == 0) m0 = mx;
            if (lane == j) { myval = mx; myidx = src; }
            if (lane == src) work = -3.402823466e38f;
        }

        float ev = (lane < TOPK) ? expf(myval - m0) : 0.f;
        float es = ev;
        es += __shfl_xor(es, 1, 64);
        es += __shfl_xor(es, 2, 64);
        es += __shfl_xor(es, 4, 64);
        if (lane < TOPK) {
            float wgt = (ev / es) * pes[myidx];
            size_t o = (size_t)(t0 + tok) * TOPK + lane;
            out_w[o] = wgt;
            out_i[o] = (float)myidx;                 // d_out read as float32
            atomicAdd(&hist[myidx], 1);
        }
    }

    __syncthreads();
    if (tid < NEXPERT)
        atomicAdd(&out_c[tid], (float)hist[tid]);    // counts are exact small ints
}

extern "C" void kernel_launch(void* const* d_in, const int* in_sizes, int n_in,
                              void* d_out, int out_size, void* d_ws, size_t ws_size,
                              hipStream_t stream) {
    const float* h     = (const float*)d_in[0];   // [4,4096,2048] f32
    const float* scale = (const float*)d_in[1];   // [2048] f32
    const float* w     = (const float*)d_in[2];   // [64,2048] f32
    const float* pes   = (const float*)d_in[3];   // [64] f32

    unsigned short* wf = (unsigned short*)d_ws;   // 512 KB f16 fragment bank

    float* out_w = (float*)d_out;                                  // [16384,8]
    float* out_i = (float*)d_out + (size_t)NTOK * TOPK;            // [16384,8] idx-as-f32
    float* out_c = (float*)d_out + (size_t)NTOK * TOPK * 2;        // [64]

    prep_wf<<<512, 256, 0, stream>>>(w, scale, wf, out_c);

    // 256 blocks x 1024 thr (16 waves); exactly 1 block/CU, 16 waves/CU
    router_main<<<NTOK / TOKB, 1024, 0, stream>>>(h, wf, pes, out_w, out_i, out_c);
}